// Round 9
// baseline (472.117 us; speedup 1.0000x reference)
//
#include <hip/hip_runtime.h>

// GAT layer, N=8192, D=256. R9: 2-tile software-pipelined flash attention.
//  - iter t: QK(t+1) [sS dbuf write] overlaps softmax(t) [sS dbuf read] with
//    NO barrier between; 2 barriers/tile total.
//  - h-hi double-buffered LDS; h-lo single buffer re-staged after the lgkm
//    barrier; g-hi in regs (32), g-lo in LDS (R5 base). vb/adj 1 tile ahead.
// Split-bf16 (hi+lo) 3-term MFMA for the logit chain; plain bf16 elsewhere.

typedef __attribute__((ext_vector_type(8))) short bf16x8;
typedef __attribute__((ext_vector_type(4))) short s16x4;
typedef __attribute__((ext_vector_type(4))) float f32x4;

#define NN 8192
#define DD 256
#define NSPLIT 4
#define NPART 4
#define CHUNK (NN / NSPLIT)
#define KVB 32
#define BM 32
#define NT (CHUNK / KVB)

#define MFMA(a, b, c) __builtin_amdgcn_mfma_f32_16x16x32_bf16(a, b, c, 0, 0, 0)
#define BAR_LGKM() asm volatile("s_waitcnt lgkmcnt(0)\n\ts_barrier" ::: "memory")
#define BAR_VM() asm volatile("s_waitcnt vmcnt(0)\n\ts_barrier" ::: "memory")

__device__ __forceinline__ short f2bf(float f) {
  union { float f; unsigned u; } v; v.f = f;
  unsigned r = v.u + 0x7fffu + ((v.u >> 16) & 1u);  // RNE
  return (short)(r >> 16);
}
__device__ __forceinline__ float bf2f(short b) {
  union { unsigned u; float f; } v; v.u = ((unsigned)(unsigned short)b) << 16;
  return v.f;
}

typedef __attribute__((address_space(3))) unsigned lds_u32;
typedef const __attribute__((address_space(1))) unsigned glb_u32;
__device__ __forceinline__ void gl2lds16(const void* g, void* l) {
  __builtin_amdgcn_global_load_lds((glb_u32*)g, (lds_u32*)l, 16, 0, 0);
}

// f32 -> (hi, lo) bf16 split, elementwise
__global__ __launch_bounds__(256) void cvt_split_kernel(const float* __restrict__ in,
                                                        short* __restrict__ hi,
                                                        short* __restrict__ lo, int n) {
  for (int i = blockIdx.x * blockDim.x + threadIdx.x; i < n; i += gridDim.x * blockDim.x) {
    float f = in[i];
    short h = f2bf(f);
    hi[i] = h;
    lo[i] = f2bf(f - bf2f(h));
  }
}

// featT[c][i] = bf16(feat[i][c]) via LDS 32x32 tile (coalesced both sides)
__global__ __launch_bounds__(256) void featT_kernel(const float* __restrict__ feat,
                                                    short* __restrict__ fT) {
  __shared__ float tile[32][33];
  const int i0 = blockIdx.x * 32, c0 = blockIdx.y * 32;
  const int r = threadIdx.x >> 5, c = threadIdx.x & 31;
#pragma unroll
  for (int p = 0; p < 4; ++p)
    tile[p * 8 + r][c] = feat[(size_t)(i0 + p * 8 + r) * DD + c0 + c];
  __syncthreads();
#pragma unroll
  for (int p = 0; p < 4; ++p)
    fT[(size_t)(c0 + p * 8 + r) * NN + i0 + c] = f2bf(tile[c][p * 8 + r]);
}

// 256x256 f32 -> transposed bf16 (optionally split hi/lo)
__global__ __launch_bounds__(256) void transpose_split_kernel(const float* __restrict__ in,
                                                              short* __restrict__ tHi,
                                                              short* __restrict__ tLo) {
  int r = blockIdx.x, c = threadIdx.x;
  float f = in[r * DD + c];
  short h = f2bf(f);
  tHi[c * DD + r] = h;
  if (tLo) tLo[c * DD + r] = f2bf(f - bf2f(h));
}

// C[64x64 tile] = A @ BT^T over K=256 (+optional split / second product / ELU)
__global__ __launch_bounds__(256) void gemm_bt64_kernel(
    const short* __restrict__ Ahi, const short* __restrict__ Alo,
    const short* __restrict__ BThi, const short* __restrict__ BTlo,
    const short* __restrict__ A2, const short* __restrict__ BT2,
    short* __restrict__ outHi, short* __restrict__ outLo,
    float* __restrict__ outF, int doElu) {
  const int lane = threadIdx.x & 63;
  const int w = threadIdx.x >> 6;
  const int l15 = lane & 15;
  const int koff = (lane >> 4) * 8;
  const int row0 = blockIdx.x * 64 + w * 16;
  const int col0 = blockIdx.y * 64;
  f32x4 acc[4] = {};
  const int aoff = (row0 + l15) * DD + koff;
#pragma unroll
  for (int kk = 0; kk < 8; ++kk) {
    bf16x8 ah = *(const bf16x8*)(Ahi + aoff + kk * 32);
#pragma unroll
    for (int cf = 0; cf < 4; ++cf) {
      int boff = (col0 + cf * 16 + l15) * DD + kk * 32 + koff;
      bf16x8 bh = *(const bf16x8*)(BThi + boff);
      acc[cf] = MFMA(ah, bh, acc[cf]);
      if (Alo) {
        bf16x8 al = *(const bf16x8*)(Alo + aoff + kk * 32);
        acc[cf] = MFMA(al, bh, acc[cf]);
      }
      if (BTlo) {
        bf16x8 bl = *(const bf16x8*)(BTlo + boff);
        acc[cf] = MFMA(ah, bl, acc[cf]);
      }
    }
  }
  if (A2) {
#pragma unroll
    for (int kk = 0; kk < 8; ++kk) {
      bf16x8 ah = *(const bf16x8*)(A2 + aoff + kk * 32);
#pragma unroll
      for (int cf = 0; cf < 4; ++cf) {
        bf16x8 bh = *(const bf16x8*)(BT2 + (col0 + cf * 16 + l15) * DD + kk * 32 + koff);
        acc[cf] = MFMA(ah, bh, acc[cf]);
      }
    }
  }
  const int crow = row0 + (lane >> 4) * 4;
#pragma unroll
  for (int cf = 0; cf < 4; ++cf) {
    int col = col0 + cf * 16 + l15;
#pragma unroll
    for (int r = 0; r < 4; ++r) {
      float v = acc[cf][r];
      if (doElu) v = (v > 0.f) ? v : expm1f(v);
      if (outF) outF[(crow + r) * DD + col] = v;
      if (outHi) {
        short hb = f2bf(v);
        outHi[(crow + r) * DD + col] = hb;
        if (outLo) outLo[(crow + r) * DD + col] = f2bf(v - bf2f(hb));
      }
    }
  }
}

// ax[i] = h[i,:]·a1, ay[i] = h[i,:]·a2
__global__ __launch_bounds__(256) void axay_kernel(const short* __restrict__ hHi,
                                                   const short* __restrict__ hLo,
                                                   const float* __restrict__ a1,
                                                   const float* __restrict__ a2,
                                                   float* __restrict__ ax,
                                                   float* __restrict__ ay) {
  const int lane = threadIdx.x & 63;
  const int w = threadIdx.x >> 6;
  const int row = blockIdx.x * 4 + w;
  float s1 = 0.f, s2 = 0.f;
#pragma unroll
  for (int j = 0; j < 4; ++j) {
    int k = lane * 4 + j;
    float hv = bf2f(hHi[row * DD + k]) + bf2f(hLo[row * DD + k]);
    s1 += hv * a1[k];
    s2 += hv * a2[k];
  }
#pragma unroll
  for (int m = 1; m < 64; m <<= 1) {
    s1 += __shfl_xor(s1, m);
    s2 += __shfl_xor(s2, m);
  }
  if (lane == 0) { ax[row] = s1; ay[row] = s2; }
}

// Pipelined flash attention, NSPLIT chunks, 32q x 32kv tiles, 4 waves.
// Iter t: QK(t) [if t<NT] overlapped with softmax/PV(t-1) [if t>0].
__global__ __launch_bounds__(256, 2) void attn_kernel(
    const short* __restrict__ gHi, const short* __restrict__ gLo,
    const short* __restrict__ hHi, const short* __restrict__ hLo,
    const short* __restrict__ fT, const float* __restrict__ ax,
    const float* __restrict__ ay, const int* __restrict__ adj,
    short* __restrict__ numPart, float* __restrict__ mPart,
    float* __restrict__ lPart) {
  __shared__ short sGlo[BM * DD];      // 16KB g-lo (512B rows, XOR-swizzled)
  __shared__ short sH[2][KVB * DD];    // 2x16KB h-hi double buffer (swizzled)
  __shared__ short sHlo[KVB * DD];     // 16KB h-lo single buffer (swizzled)
  __shared__ float sS[2][BM][36];      // 9.2KB S exchange, double buffered
  __shared__ short sP[BM][40];         // 2.5KB P exchange
  __shared__ float sScale[BM];

  const int tid = threadIdx.x;
  const int lane = tid & 63;
  const int w = tid >> 6;
  const int wr = w >> 1, sp = w & 1;  // QK: row-half, kv-strip
  const int l15 = lane & 15;
  const int q0 = lane >> 4;
  const int crow = q0 * 4;

  // XCD-pair swizzle: chunk c -> XCDs {2c, 2c+1}
  const int bid = blockIdx.x;
  const int chunk = (bid & 7) >> 1;
  const int rowblk = ((bid >> 3) << 1) | (bid & 1);
  const int row0 = rowblk * BM;
  const int jbase = chunk * CHUNK;

  // ---- hoist ghi (32 VGPR) ----
  bf16x8 ghi[8];
  {
    const int go = (row0 + wr * 16 + l15) * DD + q0 * 8;
#pragma unroll
    for (int kk = 0; kk < 8; ++kk) ghi[kk] = *(const bf16x8*)(gHi + go + kk * 32);
  }
  float ay4[4];
#pragma unroll
  for (int r = 0; r < 4; ++r) ay4[r] = ay[row0 + wr * 16 + crow + r];

  auto stage16 = [&](const short* src, char* dst, int jrow) {
#pragma unroll
    for (int R = 0; R < 4; ++R) {
      int dstb = R * 4096 + tid * 16;
      int lr = dstb >> 9;
      int srcb = (dstb & 511) ^ ((lr & 7) << 4);
      gl2lds16(src + (jrow + lr) * DD + (srcb >> 1), dst + dstb);
    }
  };

  const size_t adjrow = (size_t)(row0 + wr * 16 + crow) * NN;
  const int srow = tid >> 3;
  const int sc4 = (tid & 7) * 4;
  float m_run = -__builtin_inff();
  float l_run = 0.f;
  f32x4 accpv[2][4] = {};

  // ---- prologue: g-lo, tile0 hi+lo, adj(0) ----
  stage16(gLo, (char*)sGlo, row0 - jbase + jbase);  // rows row0.. of gLo
  // (note: stage16 uses jrow as row base; call with row0 for g)
  // re-issue correctly below for g:
  // actually: first call staged gLo rows [row0, row0+32) ✓ since jrow=row0.
  stage16(hHi, (char*)sH[0], jbase);
  stage16(hLo, (char*)sHlo, jbase);
  int a4[4];
  float axv;
  {
    int kb = jbase + sp * 16 + l15;
#pragma unroll
    for (int r = 0; r < 4; ++r) a4[r] = adj[adjrow + (size_t)r * NN + kb];
    axv = ax[kb];
  }
  bf16x8 vb[4];
  BAR_VM();  // all prologue staging complete

  for (int t = 0; t <= NT; ++t) {
    const int j0 = jbase + t * KVB;
    // ---- issue adj(t+1) early (long HBM latency) + stage hi(t+1) ----
    int a4n[4];
    float axn;
    if (t + 1 < NT) {
      int kb = j0 + KVB + sp * 16 + l15;
#pragma unroll
      for (int r = 0; r < 4; ++r) a4n[r] = adj[adjrow + (size_t)r * NN + kb];
      axn = ax[kb];
      stage16(hHi, (char*)sH[(t + 1) & 1], j0 + KVB);
    }
    // ---- QK(t): 3-term split, operands from LDS (+ghi regs) ----
    if (t < NT) {
      f32x4 aA = {}, aB = {};
      const int lrB = sp * 16 + l15;
      const int rbB = lrB * 512, swzB = (lrB & 7) << 4;
      const int lrA = wr * 16 + l15;
      const int rbA = lrA * 512, swzA = (lrA & 7) << 4;
      const char* sHb = (const char*)sH[t & 1];
      __builtin_amdgcn_s_setprio(1);
#pragma unroll
      for (int kk = 0; kk < 8; ++kk) {
        const int slot = kk * 64 + q0 * 16;
        bf16x8 bh = *(const bf16x8*)(sHb + rbB + (slot ^ swzB));
        bf16x8 bl = *(const bf16x8*)((const char*)sHlo + rbB + (slot ^ swzB));
        bf16x8 gl = *(const bf16x8*)((const char*)sGlo + rbA + (slot ^ swzA));
        if (kk & 1) {
          aB = MFMA(ghi[kk], bh, aB); aB = MFMA(gl, bh, aB); aB = MFMA(ghi[kk], bl, aB);
        } else {
          aA = MFMA(ghi[kk], bh, aA); aA = MFMA(gl, bh, aA); aA = MFMA(ghi[kk], bl, aA);
        }
      }
      __builtin_amdgcn_s_setprio(0);
      // mask + bias + leaky -> sS[t&1]
#pragma unroll
      for (int r = 0; r < 4; ++r) {
        float v = aA[r] + aB[r] + axv + ay4[r];
        v = (v > 0.f) ? v : 0.2f * v;
        sS[t & 1][wr * 16 + crow + r][sp * 16 + l15] = (a4[r] > 0) ? v : -9.0e15f;
      }
    }
    // ---- softmax(t-1) from sS[(t-1)&1] (overlaps QK(t) above) ----
    if (t > 0) {
      float4 sv = *(const float4*)(&sS[(t - 1) & 1][srow][sc4]);
      float tmax = fmaxf(fmaxf(sv.x, sv.y), fmaxf(sv.z, sv.w));
      tmax = fmaxf(tmax, __shfl_xor(tmax, 1));
      tmax = fmaxf(tmax, __shfl_xor(tmax, 2));
      tmax = fmaxf(tmax, __shfl_xor(tmax, 4));
      float m_new = fmaxf(m_run, tmax);
      float scale = __expf(m_run - m_new);
      float p0 = __expf(sv.x - m_new), p1 = __expf(sv.y - m_new);
      float p2 = __expf(sv.z - m_new), p3 = __expf(sv.w - m_new);
      float psum = (p0 + p1) + (p2 + p3);
      psum += __shfl_xor(psum, 1);
      psum += __shfl_xor(psum, 2);
      psum += __shfl_xor(psum, 4);
      l_run = l_run * scale + psum;
      m_run = m_new;
      s16x4 pk = { f2bf(p0), f2bf(p1), f2bf(p2), f2bf(p3) };
      *(s16x4*)(&sP[srow][sc4]) = pk;
      if ((tid & 7) == 0) sScale[srow] = scale;
    }
    BAR_LGKM();  // sP/sScale visible; all QK(t) LDS reads (incl sHlo) done
    // ---- re-stage h-lo(t+1) into the single buffer (safe after barrier) ----
    if (t + 1 < NT) stage16(hLo, (char*)sHlo, j0 + KVB);
    // ---- PV(t-1): rescale + 8 MFMA (vb loaded last iter) ----
    if (t > 0) {
      float4 sc0 = *(const float4*)(&sScale[crow]);
      float4 sc1 = *(const float4*)(&sScale[16 + crow]);
      const float* scp[2] = { &sc0.x, &sc1.x };
#pragma unroll
      for (int rg = 0; rg < 2; ++rg)
#pragma unroll
        for (int df = 0; df < 4; ++df)
#pragma unroll
          for (int r = 0; r < 4; ++r) accpv[rg][df][r] *= scp[rg][r];
      bf16x8 pa0 = *(const bf16x8*)(&sP[l15][q0 * 8]);
      bf16x8 pa1 = *(const bf16x8*)(&sP[16 + l15][q0 * 8]);
      __builtin_amdgcn_s_setprio(1);
#pragma unroll
      for (int df = 0; df < 4; ++df) {
        accpv[0][df] = MFMA(pa0, vb[df], accpv[0][df]);
        accpv[1][df] = MFMA(pa1, vb[df], accpv[1][df]);
      }
      __builtin_amdgcn_s_setprio(0);
    }
    // ---- load vb(t) for next iter's PV(t) (regs freed by PV above) ----
    if (t < NT) {
#pragma unroll
      for (int df = 0; df < 4; ++df)
        vb[df] = *(const bf16x8*)(fT + (size_t)(w * 64 + df * 16 + l15) * NN + j0 + q0 * 8);
    }
    // rotate adj prefetch
#pragma unroll
    for (int r = 0; r < 4; ++r) a4[r] = a4n[r];
    axv = axn;
    BAR_VM();  // stage(t+1) + vb(t) + adj(t+1) complete; sS[t&1] visible
  }
  // ---- emit partials ----
  if ((tid & 7) == 0) {
    mPart[chunk * NN + row0 + srow] = m_run;
    lPart[chunk * NN + row0 + srow] = l_run;
  }
  short* np = numPart + (size_t)chunk * NN * DD;
#pragma unroll
  for (int rg = 0; rg < 2; ++rg)
#pragma unroll
    for (int df = 0; df < 4; ++df) {
      int col = w * 64 + df * 16 + l15;
#pragma unroll
      for (int r = 0; r < 4; ++r)
        np[(size_t)(row0 + rg * 16 + crow + r) * DD + col] = f2bf(accpv[rg][df][r]);
    }
}

// hp = (sum_i num_i * exp(m_i - m*)) / (sum_i l_i * exp(m_i - m*))
__global__ __launch_bounds__(256) void combine_kernel(
    const short* __restrict__ numPart, const float* __restrict__ mPart,
    const float* __restrict__ lPart, short* __restrict__ hp) {
  const int row = blockIdx.x;
  const int col = threadIdx.x;
  float m[NPART], l[NPART];
  float ms = -__builtin_inff();
#pragma unroll
  for (int i = 0; i < NPART; ++i) {
    m[i] = mPart[i * NN + row];
    l[i] = lPart[i * NN + row];
    ms = fmaxf(ms, m[i]);
  }
  float denom = 0.f, num = 0.f;
  const size_t idx = (size_t)row * DD + col;
#pragma unroll
  for (int i = 0; i < NPART; ++i) {
    float wgt = __expf(m[i] - ms);
    denom += l[i] * wgt;
    num += bf2f(numPart[(size_t)i * NN * DD + idx]) * wgt;
  }
  hp[idx] = f2bf(num / denom);
}

extern "C" void kernel_launch(void* const* d_in, const int* in_sizes, int n_in,
                              void* d_out, int out_size, void* d_ws, size_t ws_size,
                              hipStream_t stream) {
  const float* feat = (const float*)d_in[0];
  const int*   adj  = (const int*)d_in[1];
  const float* W    = (const float*)d_in[2];
  const float* a1   = (const float*)d_in[3];
  const float* a2   = (const float*)d_in[4];
  const float* a12  = (const float*)d_in[5];
  const float* W1   = (const float*)d_in[6];
  const float* W2   = (const float*)d_in[7];
  float* out = (float*)d_out;
  (void)in_sizes; (void)n_in; (void)out_size; (void)ws_size;

  char* ws = (char*)d_ws;
  size_t off = 0;
  auto alloc = [&](size_t b) { void* p = ws + off; off += (b + 255) & ~(size_t)255; return p; };
  short* featHi = (short*)alloc((size_t)NN * DD * 2);
  short* featLo = (short*)alloc((size_t)NN * DD * 2);
  short* fT     = (short*)alloc((size_t)NN * DD * 2);
  short* hHi    = (short*)alloc((size_t)NN * DD * 2);
  short* hLo    = (short*)alloc((size_t)NN * DD * 2);
  short* gHi    = (short*)alloc((size_t)NN * DD * 2);
  short* gLo    = (short*)alloc((size_t)NN * DD * 2);
  short* hp     = (short*)alloc((size_t)NN * DD * 2);
  short* WTh    = (short*)alloc((size_t)DD * DD * 2);
  short* WTl    = (short*)alloc((size_t)DD * DD * 2);
  short* A12Th  = (short*)alloc((size_t)DD * DD * 2);
  short* A12Tl  = (short*)alloc((size_t)DD * DD * 2);
  short* W1T    = (short*)alloc((size_t)DD * DD * 2);
  short* W2T    = (short*)alloc((size_t)DD * DD * 2);
  float* axv    = (float*)alloc((size_t)NN * 4);
  float* ayv    = (float*)alloc((size_t)NN * 4);
  short* numPart = (short*)alloc((size_t)NPART * NN * DD * 2);
  float* mPart   = (float*)alloc((size_t)NPART * NN * 4);
  float* lPart   = (float*)alloc((size_t)NPART * NN * 4);

  cvt_split_kernel<<<2048, 256, 0, stream>>>(feat, featHi, featLo, NN * DD);
  featT_kernel<<<dim3(NN / 32, DD / 32), 256, 0, stream>>>(feat, fT);
  transpose_split_kernel<<<DD, DD, 0, stream>>>(W, WTh, WTl);
  transpose_split_kernel<<<DD, DD, 0, stream>>>(a12, A12Th, A12Tl);
  transpose_split_kernel<<<DD, DD, 0, stream>>>(W1, W1T, nullptr);
  transpose_split_kernel<<<DD, DD, 0, stream>>>(W2, W2T, nullptr);
  gemm_bt64_kernel<<<dim3(NN / 64, DD / 64), 256, 0, stream>>>(
      featHi, featLo, WTh, WTl, nullptr, nullptr, hHi, hLo, nullptr, 0);
  gemm_bt64_kernel<<<dim3(NN / 64, DD / 64), 256, 0, stream>>>(
      hHi, hLo, A12Th, A12Tl, nullptr, nullptr, gHi, gLo, nullptr, 0);
  axay_kernel<<<NN / 4, 256, 0, stream>>>(hHi, hLo, a1, a2, axv, ayv);
  attn_kernel<<<dim3((NN / BM) * NSPLIT), 256, 0, stream>>>(
      gHi, gLo, hHi, hLo, fT, axv, ayv, adj, numPart, mPart, lPart);
  combine_kernel<<<NN, DD, 0, stream>>>(numPart, mPart, lPart, hp);
  gemm_bt64_kernel<<<dim3(NN / 64, DD / 64), 256, 0, stream>>>(
      featHi, nullptr, W1T, nullptr, hp, W2T, nullptr, nullptr, out, 1);
}

// Round 10
// 307.667 us; speedup vs baseline: 1.5345x; 1.5345x over previous
//
#include <hip/hip_runtime.h>

// GAT layer, N=8192, D=256. R10: fp16 end-to-end numerics.
//  - h,g via split-fp16 3-term GEMMs (f32-grade), stored fp16 single.
//  - QK^T = SINGLE fp16 MFMA (16/wave per 64-col tile, was 48 bf16-split).
//  - KVB=64 (half the barriers); g fp16 in LDS; h fp16 single LDS buffer.
//  - PV/output path fp16 (smaller base error than bf16).
// Proven R5/R8 discipline: vb issued before stage (vmcnt), adj prefetch 1
// tile ahead, XOR-swizzled LDS, XCD-pair swizzle, NSPLIT=4 partials.

typedef __attribute__((ext_vector_type(8))) _Float16 f16x8;
typedef __attribute__((ext_vector_type(4))) float f32x4;

#define NN 8192
#define DD 256
#define NSPLIT 4
#define NPART 4
#define CHUNK (NN / NSPLIT)
#define KVB 64
#define BM 32
#define NT (CHUNK / KVB)

#define MFMA16(a, b, c) __builtin_amdgcn_mfma_f32_16x16x32_f16(a, b, c, 0, 0, 0)
#define BAR_LGKM() asm volatile("s_waitcnt lgkmcnt(0)\n\ts_barrier" ::: "memory")
#define BAR_VM() asm volatile("s_waitcnt vmcnt(0)\n\ts_barrier" ::: "memory")

__device__ __forceinline__ short f2h(float f) {
  union { _Float16 h; short s; } u; u.h = (_Float16)f; return u.s;
}
__device__ __forceinline__ float h2f(short b) {
  union { short s; _Float16 h; } u; u.s = b; return (float)u.h;
}

typedef __attribute__((address_space(3))) unsigned lds_u32;
typedef const __attribute__((address_space(1))) unsigned glb_u32;
__device__ __forceinline__ void gl2lds16(const void* g, void* l) {
  __builtin_amdgcn_global_load_lds((glb_u32*)g, (lds_u32*)l, 16, 0, 0);
}

// f32 -> (hi, lo) fp16 split, elementwise
__global__ __launch_bounds__(256) void cvt_split_kernel(const float* __restrict__ in,
                                                        short* __restrict__ hi,
                                                        short* __restrict__ lo, int n) {
  for (int i = blockIdx.x * blockDim.x + threadIdx.x; i < n; i += gridDim.x * blockDim.x) {
    float f = in[i];
    short h = f2h(f);
    hi[i] = h;
    lo[i] = f2h(f - h2f(h));
  }
}

// featT[c][i] = f16(feat[i][c]) via LDS 32x32 tile (coalesced both sides)
__global__ __launch_bounds__(256) void featT_kernel(const float* __restrict__ feat,
                                                    short* __restrict__ fT) {
  __shared__ float tile[32][33];
  const int i0 = blockIdx.x * 32, c0 = blockIdx.y * 32;
  const int r = threadIdx.x >> 5, c = threadIdx.x & 31;
#pragma unroll
  for (int p = 0; p < 4; ++p)
    tile[p * 8 + r][c] = feat[(size_t)(i0 + p * 8 + r) * DD + c0 + c];
  __syncthreads();
#pragma unroll
  for (int p = 0; p < 4; ++p)
    fT[(size_t)(c0 + p * 8 + r) * NN + i0 + c] = f2h(tile[c][p * 8 + r]);
}

// 256x256 f32 -> transposed fp16 (optionally split hi/lo)
__global__ __launch_bounds__(256) void transpose_split_kernel(const float* __restrict__ in,
                                                              short* __restrict__ tHi,
                                                              short* __restrict__ tLo) {
  int r = blockIdx.x, c = threadIdx.x;
  float f = in[r * DD + c];
  short h = f2h(f);
  tHi[c * DD + r] = h;
  if (tLo) tLo[c * DD + r] = f2h(f - h2f(h));
}

// C[64x64 tile] = A @ BT^T over K=256, fp16 MFMA.
// Optional split (Alo/BTlo terms), second product (A2@BT2), ELU epilogue.
__global__ __launch_bounds__(256) void gemm_kernel(
    const short* __restrict__ Ahi, const short* __restrict__ Alo,
    const short* __restrict__ BThi, const short* __restrict__ BTlo,
    const short* __restrict__ A2, const short* __restrict__ BT2,
    short* __restrict__ outH, float* __restrict__ outF, int doElu) {
  const int lane = threadIdx.x & 63;
  const int w = threadIdx.x >> 6;
  const int l15 = lane & 15;
  const int koff = (lane >> 4) * 8;
  const int row0 = blockIdx.x * 64 + w * 16;
  const int col0 = blockIdx.y * 64;
  f32x4 acc[4] = {};
  const int aoff = (row0 + l15) * DD + koff;
#pragma unroll
  for (int kk = 0; kk < 8; ++kk) {
    f16x8 ah = *(const f16x8*)(Ahi + aoff + kk * 32);
#pragma unroll
    for (int cf = 0; cf < 4; ++cf) {
      int boff = (col0 + cf * 16 + l15) * DD + kk * 32 + koff;
      f16x8 bh = *(const f16x8*)(BThi + boff);
      acc[cf] = MFMA16(ah, bh, acc[cf]);
      if (Alo) {
        f16x8 al = *(const f16x8*)(Alo + aoff + kk * 32);
        acc[cf] = MFMA16(al, bh, acc[cf]);
      }
      if (BTlo) {
        f16x8 bl = *(const f16x8*)(BTlo + boff);
        acc[cf] = MFMA16(ah, bl, acc[cf]);
      }
    }
  }
  if (A2) {
#pragma unroll
    for (int kk = 0; kk < 8; ++kk) {
      f16x8 ah = *(const f16x8*)(A2 + aoff + kk * 32);
#pragma unroll
      for (int cf = 0; cf < 4; ++cf) {
        f16x8 bh = *(const f16x8*)(BT2 + (col0 + cf * 16 + l15) * DD + kk * 32 + koff);
        acc[cf] = MFMA16(ah, bh, acc[cf]);
      }
    }
  }
  const int crow = row0 + (lane >> 4) * 4;
#pragma unroll
  for (int cf = 0; cf < 4; ++cf) {
    int col = col0 + cf * 16 + l15;
#pragma unroll
    for (int r = 0; r < 4; ++r) {
      float v = acc[cf][r];
      if (doElu) v = (v > 0.f) ? v : expm1f(v);
      if (outF) outF[(crow + r) * DD + col] = v;
      if (outH) outH[(crow + r) * DD + col] = f2h(v);
    }
  }
}

// ax[i] = h[i,:]·a1, ay[i] = h[i,:]·a2  (h fp16)
__global__ __launch_bounds__(256) void axay_kernel(const short* __restrict__ hF,
                                                   const float* __restrict__ a1,
                                                   const float* __restrict__ a2,
                                                   float* __restrict__ ax,
                                                   float* __restrict__ ay) {
  const int lane = threadIdx.x & 63;
  const int w = threadIdx.x >> 6;
  const int row = blockIdx.x * 4 + w;
  float s1 = 0.f, s2 = 0.f;
#pragma unroll
  for (int j = 0; j < 4; ++j) {
    int k = lane * 4 + j;
    float hv = h2f(hF[row * DD + k]);
    s1 += hv * a1[k];
    s2 += hv * a2[k];
  }
#pragma unroll
  for (int m = 1; m < 64; m <<= 1) {
    s1 += __shfl_xor(s1, m);
    s2 += __shfl_xor(s2, m);
  }
  if (lane == 0) { ax[row] = s1; ay[row] = s2; }
}

// Flash attention, fp16 single-MFMA logit path. 32q x 64kv tiles, 4 waves.
// Wave (wr,sp): QK rows wr*16, cols sp*32 + {0,16}. PV: 32q x 64d per wave.
__global__ __launch_bounds__(256, 2) void attn_kernel(
    const short* __restrict__ gF, const short* __restrict__ hF,
    const short* __restrict__ fT, const float* __restrict__ ax,
    const float* __restrict__ ay, const int* __restrict__ adj,
    short* __restrict__ numPart, float* __restrict__ mPart,
    float* __restrict__ lPart) {
  __shared__ short sG[BM * DD];     // 16KB g tile (512B rows, XOR-swizzled)
  __shared__ short sH[KVB * DD];    // 32KB h tile (512B rows, XOR-swizzled)
  __shared__ float sS[BM][68];      // 8.7KB S exchange (272B rows, 16B-mult)
  __shared__ short sP[BM][80];      // 5KB P exchange (160B rows, 16B-mult)
  __shared__ float sScale[BM];

  const int tid = threadIdx.x;
  const int lane = tid & 63;
  const int w = tid >> 6;
  const int wr = w >> 1, sp = w & 1;
  const int l15 = lane & 15;
  const int q0 = lane >> 4;
  const int crow = q0 * 4;

  // XCD-pair swizzle: chunk c -> XCDs {2c, 2c+1}
  const int bid = blockIdx.x;
  const int chunk = (bid & 7) >> 1;
  const int rowblk = ((bid >> 3) << 1) | (bid & 1);
  const int row0 = rowblk * BM;
  const int jbase = chunk * CHUNK;

  float ay4[4];
#pragma unroll
  for (int r = 0; r < 4; ++r) ay4[r] = ay[row0 + wr * 16 + crow + r];

  // ---- stage g block (once) + h tile 0, XOR-swizzled ----
#pragma unroll
  for (int R = 0; R < 4; ++R) {
    int dstb = R * 4096 + tid * 16;
    int lr = dstb >> 9;
    int srcb = (dstb & 511) ^ ((lr & 7) << 4);
    gl2lds16(gF + (row0 + lr) * DD + (srcb >> 1), (char*)sG + dstb);
  }
  auto stageH = [&](int jrow) {
#pragma unroll
    for (int R = 0; R < 8; ++R) {
      int dstb = R * 4096 + tid * 16;
      int lr = dstb >> 9;
      int srcb = (dstb & 511) ^ ((lr & 7) << 4);
      gl2lds16(hF + (jrow + lr) * DD + (srcb >> 1), (char*)sH + dstb);
    }
  };
  stageH(jbase);

  const size_t adjrow = (size_t)(row0 + wr * 16 + crow) * NN;
  // ---- adj/ax prefetch for tile 0 ----
  int a8[2][4];
  float ax2[2];
#pragma unroll
  for (int cf = 0; cf < 2; ++cf) {
    int kb = jbase + sp * 32 + cf * 16 + l15;
#pragma unroll
    for (int r = 0; r < 4; ++r) a8[cf][r] = adj[adjrow + (size_t)r * NN + kb];
    ax2[cf] = ax[kb];
  }

  const int srow = tid >> 3;
  const int sc8 = (tid & 7) * 8;
  float m_run = -__builtin_inff();
  float l_run = 0.f;
  f32x4 accpv[2][4] = {};  // [rg][df]: rows rg*16+crow+r, dims w*64+df*16+l15

  BAR_VM();  // sG + sH(0) staged

  for (int t = 0; t < NT; ++t) {
    const int j0 = jbase + t * KVB;
    // ---- QK^T: single fp16 MFMA, A=g(LDS) B=h(LDS) ----
    f32x4 aA = {}, aB = {};
    {
      const int lrA = wr * 16 + l15;
      const int rbA = lrA * 512, swzA = (lrA & 7) << 4;
      const int lrB0 = sp * 32 + l15;
      const int rbB0 = lrB0 * 512, swzB0 = (lrB0 & 7) << 4;
      const int lrB1 = sp * 32 + 16 + l15;
      const int rbB1 = lrB1 * 512, swzB1 = (lrB1 & 7) << 4;
      __builtin_amdgcn_s_setprio(1);
#pragma unroll
      for (int kk = 0; kk < 8; ++kk) {
        const int slot = kk * 64 + q0 * 16;
        f16x8 ga = *(const f16x8*)((const char*)sG + rbA + (slot ^ swzA));
        f16x8 b0 = *(const f16x8*)((const char*)sH + rbB0 + (slot ^ swzB0));
        f16x8 b1 = *(const f16x8*)((const char*)sH + rbB1 + (slot ^ swzB1));
        aA = MFMA16(ga, b0, aA);
        aB = MFMA16(ga, b1, aB);
      }
      __builtin_amdgcn_s_setprio(0);
    }
    // ---- mask + bias + leaky -> sS ----
#pragma unroll
    for (int cf = 0; cf < 2; ++cf) {
      const f32x4& ac = cf ? aB : aA;
#pragma unroll
      for (int r = 0; r < 4; ++r) {
        float v = ac[r] + ax2[cf] + ay4[r];
        v = (v > 0.f) ? v : 0.2f * v;
        sS[wr * 16 + crow + r][sp * 32 + cf * 16 + l15] =
            (a8[cf][r] > 0) ? v : -9.0e15f;
      }
    }
    BAR_LGKM();  // sS visible; sG/sH reads done
    // ---- vb + adj(t+1) issued BEFORE stage (vmcnt: PV waits only vb) ----
    f16x8 vb[2][4];
#pragma unroll
    for (int ks = 0; ks < 2; ++ks)
#pragma unroll
      for (int df = 0; df < 4; ++df)
        vb[ks][df] = *(const f16x8*)(fT + (size_t)(w * 64 + df * 16 + l15) * NN +
                                     j0 + ks * 32 + q0 * 8);
    int a8n[2][4];
    float ax2n[2];
    {
      int jn = (t + 1 < NT) ? (j0 + KVB) : jbase;
#pragma unroll
      for (int cf = 0; cf < 2; ++cf) {
        int kb = jn + sp * 32 + cf * 16 + l15;
#pragma unroll
        for (int r = 0; r < 4; ++r) a8n[cf][r] = adj[adjrow + (size_t)r * NN + kb];
        ax2n[cf] = ax[kb];
      }
    }
    if (t + 1 < NT) stageH(j0 + KVB);
    // ---- softmax: 8 threads/row, 8 cols each ----
    {
      float4 s0 = *(const float4*)(&sS[srow][sc8]);
      float4 s1 = *(const float4*)(&sS[srow][sc8 + 4]);
      float tmax = fmaxf(fmaxf(fmaxf(s0.x, s0.y), fmaxf(s0.z, s0.w)),
                         fmaxf(fmaxf(s1.x, s1.y), fmaxf(s1.z, s1.w)));
      tmax = fmaxf(tmax, __shfl_xor(tmax, 1));
      tmax = fmaxf(tmax, __shfl_xor(tmax, 2));
      tmax = fmaxf(tmax, __shfl_xor(tmax, 4));
      float m_new = fmaxf(m_run, tmax);
      float scale = __expf(m_run - m_new);
      float p[8];
      p[0] = __expf(s0.x - m_new); p[1] = __expf(s0.y - m_new);
      p[2] = __expf(s0.z - m_new); p[3] = __expf(s0.w - m_new);
      p[4] = __expf(s1.x - m_new); p[5] = __expf(s1.y - m_new);
      p[6] = __expf(s1.z - m_new); p[7] = __expf(s1.w - m_new);
      float psum = ((p[0] + p[1]) + (p[2] + p[3])) + ((p[4] + p[5]) + (p[6] + p[7]));
      psum += __shfl_xor(psum, 1);
      psum += __shfl_xor(psum, 2);
      psum += __shfl_xor(psum, 4);
      l_run = l_run * scale + psum;
      m_run = m_new;
      union { short s[8]; f16x8 v; } pu;
#pragma unroll
      for (int c = 0; c < 8; ++c) pu.s[c] = f2h(p[c]);
      *(f16x8*)(&sP[srow][sc8]) = pu.v;
      if ((tid & 7) == 0) sScale[srow] = scale;
    }
    BAR_LGKM();  // sP/sScale visible
    // ---- PV: rescale + 16 MFMA ----
    {
      float4 sc0 = *(const float4*)(&sScale[crow]);
      float4 sc1 = *(const float4*)(&sScale[16 + crow]);
      const float* scp[2] = { &sc0.x, &sc1.x };
#pragma unroll
      for (int rg = 0; rg < 2; ++rg)
#pragma unroll
        for (int df = 0; df < 4; ++df)
#pragma unroll
          for (int r = 0; r < 4; ++r) accpv[rg][df][r] *= scp[rg][r];
      __builtin_amdgcn_s_setprio(1);
#pragma unroll
      for (int ks = 0; ks < 2; ++ks) {
        f16x8 pa0 = *(const f16x8*)(&sP[l15][ks * 32 + q0 * 8]);
        f16x8 pa1 = *(const f16x8*)(&sP[16 + l15][ks * 32 + q0 * 8]);
#pragma unroll
        for (int df = 0; df < 4; ++df) {
          accpv[0][df] = MFMA16(pa0, vb[ks][df], accpv[0][df]);
          accpv[1][df] = MFMA16(pa1, vb[ks][df], accpv[1][df]);
        }
      }
      __builtin_amdgcn_s_setprio(0);
    }
    // rotate adj/ax prefetch
#pragma unroll
    for (int cf = 0; cf < 2; ++cf) {
#pragma unroll
      for (int r = 0; r < 4; ++r) a8[cf][r] = a8n[cf][r];
      ax2[cf] = ax2n[cf];
    }
    BAR_VM();  // stage(t+1) done; sP consumed; sS free
  }
  // ---- emit partials ----
  if ((tid & 7) == 0) {
    mPart[chunk * NN + row0 + srow] = m_run;
    lPart[chunk * NN + row0 + srow] = l_run;
  }
  short* np = numPart + (size_t)chunk * NN * DD;
#pragma unroll
  for (int rg = 0; rg < 2; ++rg)
#pragma unroll
    for (int df = 0; df < 4; ++df) {
      int col = w * 64 + df * 16 + l15;
#pragma unroll
      for (int r = 0; r < 4; ++r)
        np[(size_t)(row0 + rg * 16 + crow + r) * DD + col] = f2h(accpv[rg][df][r]);
    }
}

// hp = (sum_i num_i * exp(m_i - m*)) / (sum_i l_i * exp(m_i - m*))
__global__ __launch_bounds__(256) void combine_kernel(
    const short* __restrict__ numPart, const float* __restrict__ mPart,
    const float* __restrict__ lPart, short* __restrict__ hp) {
  const int row = blockIdx.x;
  const int col = threadIdx.x;
  float m[NPART], l[NPART];
  float ms = -__builtin_inff();
#pragma unroll
  for (int i = 0; i < NPART; ++i) {
    m[i] = mPart[i * NN + row];
    l[i] = lPart[i * NN + row];
    ms = fmaxf(ms, m[i]);
  }
  float denom = 0.f, num = 0.f;
  const size_t idx = (size_t)row * DD + col;
#pragma unroll
  for (int i = 0; i < NPART; ++i) {
    float wgt = __expf(m[i] - ms);
    denom += l[i] * wgt;
    num += h2f(numPart[(size_t)i * NN * DD + idx]) * wgt;
  }
  hp[idx] = f2h(num / denom);
}

extern "C" void kernel_launch(void* const* d_in, const int* in_sizes, int n_in,
                              void* d_out, int out_size, void* d_ws, size_t ws_size,
                              hipStream_t stream) {
  const float* feat = (const float*)d_in[0];
  const int*   adj  = (const int*)d_in[1];
  const float* W    = (const float*)d_in[2];
  const float* a1   = (const float*)d_in[3];
  const float* a2   = (const float*)d_in[4];
  const float* a12  = (const float*)d_in[5];
  const float* W1   = (const float*)d_in[6];
  const float* W2   = (const float*)d_in[7];
  float* out = (float*)d_out;
  (void)in_sizes; (void)n_in; (void)out_size; (void)ws_size;

  char* ws = (char*)d_ws;
  size_t off = 0;
  auto alloc = [&](size_t b) { void* p = ws + off; off += (b + 255) & ~(size_t)255; return p; };
  short* featHi = (short*)alloc((size_t)NN * DD * 2);
  short* featLo = (short*)alloc((size_t)NN * DD * 2);
  short* fT     = (short*)alloc((size_t)NN * DD * 2);
  short* hF     = (short*)alloc((size_t)NN * DD * 2);
  short* gF     = (short*)alloc((size_t)NN * DD * 2);
  short* hp     = (short*)alloc((size_t)NN * DD * 2);
  short* WTh    = (short*)alloc((size_t)DD * DD * 2);
  short* WTl    = (short*)alloc((size_t)DD * DD * 2);
  short* A12Th  = (short*)alloc((size_t)DD * DD * 2);
  short* A12Tl  = (short*)alloc((size_t)DD * DD * 2);
  short* W1T    = (short*)alloc((size_t)DD * DD * 2);
  short* W2T    = (short*)alloc((size_t)DD * DD * 2);
  float* axv    = (float*)alloc((size_t)NN * 4);
  float* ayv    = (float*)alloc((size_t)NN * 4);
  short* numPart = (short*)alloc((size_t)NPART * NN * DD * 2);
  float* mPart   = (float*)alloc((size_t)NPART * NN * 4);
  float* lPart   = (float*)alloc((size_t)NPART * NN * 4);

  cvt_split_kernel<<<2048, 256, 0, stream>>>(feat, featHi, featLo, NN * DD);
  featT_kernel<<<dim3(NN / 32, DD / 32), 256, 0, stream>>>(feat, fT);
  transpose_split_kernel<<<DD, DD, 0, stream>>>(W, WTh, WTl);
  transpose_split_kernel<<<DD, DD, 0, stream>>>(a12, A12Th, A12Tl);
  transpose_split_kernel<<<DD, DD, 0, stream>>>(W1, W1T, nullptr);
  transpose_split_kernel<<<DD, DD, 0, stream>>>(W2, W2T, nullptr);
  // h = feat @ W (split-fp16 3-term), stored fp16
  gemm_kernel<<<dim3(NN / 64, DD / 64), 256, 0, stream>>>(
      featHi, featLo, WTh, WTl, nullptr, nullptr, hF, nullptr, 0);
  // g = h @ a12 (h fp16 single x split a12 -> 2-term), stored fp16
  gemm_kernel<<<dim3(NN / 64, DD / 64), 256, 0, stream>>>(
      hF, nullptr, A12Th, A12Tl, nullptr, nullptr, gF, nullptr, 0);
  axay_kernel<<<NN / 4, 256, 0, stream>>>(hF, a1, a2, axv, ayv);
  attn_kernel<<<dim3((NN / BM) * NSPLIT), 256, 0, stream>>>(
      gF, hF, fT, axv, ayv, adj, numPart, mPart, lPart);
  combine_kernel<<<NN, DD, 0, stream>>>(numPart, mPart, lPart, hp);
  // out = elu(feat@W1 + h'@W2)
  gemm_kernel<<<dim3(NN / 64, DD / 64), 256, 0, stream>>>(
      featHi, nullptr, W1T, nullptr, hp, W2T, nullptr, out, 1);
}